// Round 6
// baseline (696.928 us; speedup 1.0000x reference)
//
#include <hip/hip_runtime.h>

typedef __bf16 bf16x8 __attribute__((ext_vector_type(8)));
typedef float f32x4 __attribute__((ext_vector_type(4)));

#define HW 9216
#define ZSLAB 9216   // packed 96*96 elems per (sl,ch,img) slab — no pads
#define XTILE 32768  // shorts per xb/Wsb tile: 32 chunks x 128 rows x 8 elems

__device__ __forceinline__ unsigned short f2bf(float f) {
  unsigned u = __float_as_uint(f);
  unsigned r = (u + 0x7FFFu + ((u >> 16) & 1u)) >> 16;
  return (unsigned short)r;
}
__device__ __forceinline__ float bf2f(unsigned short h) {
  return __uint_as_float(((unsigned)h) << 16);
}

__device__ __forceinline__ void async16(const unsigned short* g, unsigned short* l) {
  __builtin_amdgcn_global_load_lds(
      (const __attribute__((address_space(1))) unsigned int*)g,
      (__attribute__((address_space(3))) unsigned int*)l, 16, 0, 0);
}

// y[j] += w[j] * z[O+j], z drawn from the 16-elem window {lo,hi}, O compile-time
template <int O>
__device__ __forceinline__ void tapfma(float* y, uint4 lo, uint4 hi, uint4 wv) {
  const unsigned short* lu = (const unsigned short*)&lo;
  const unsigned short* hu = (const unsigned short*)&hi;
  const unsigned short* wu = (const unsigned short*)&wv;
#pragma unroll
  for (int j = 0; j < 8; ++j) {
    unsigned short zz = (O + j < 8) ? lu[O + j] : hu[O + j - 8];
    y[j] += bf2f(wu[j]) * bf2f(zz);
  }
}

// one 9-tap branch on packed z, 8 px starting at w0.
// Invalid rows/windows redirect their load INDEX to a zeroed guard region
// (exact-zero contribution). Union windows shared across the 3 taps per row.
// ALL indices compile-time; y must be a named register array at the call site.
template <int B, int D>
__device__ __forceinline__ void branch8(float* y, const unsigned short* __restrict__ z,
                                        unsigned slab, unsigned guard,
                                        const unsigned short* __restrict__ gb,
                                        int h, int w0) {
  constexpr int NW = (D == 12 || D == 36) ? 5 : 3;
  int cc[NW];
  if constexpr (D == 1 || D == 6) {
    cc[0] = w0 - 8; cc[1] = w0; cc[2] = w0 + 8;
  } else if constexpr (D == 12) {
    cc[0] = w0 - 16; cc[1] = w0 - 8; cc[2] = w0; cc[3] = w0 + 8; cc[4] = w0 + 16;
  } else if constexpr (D == 24) {
    cc[0] = w0 - 24; cc[1] = w0; cc[2] = w0 + 24;
  } else {  // 36
    cc[0] = w0 - 40; cc[1] = w0 - 32; cc[2] = w0; cc[3] = w0 + 32; cc[4] = w0 + 40;
  }
  bool cv[NW];
#pragma unroll
  for (int k = 0; k < NW; ++k) cv[k] = ((unsigned)cc[k] <= 88u);

#pragma unroll
  for (int r = 0; r < 3; ++r) {
    int hh = h + (r - 1) * D;
    bool rv = ((unsigned)hh < 96u);
    unsigned rbase = slab + (unsigned)(hh * 96);
    uint4 W[NW];
#pragma unroll
    for (int k = 0; k < NW; ++k) {
      unsigned idx = (rv && cv[k]) ? (rbase + (unsigned)cc[k]) : guard;
      W[k] = *(const uint4*)(z + idx);
    }
    const int K0 = (B - 1) * 9 + r * 3;
    uint4 wv0 = *(const uint4*)(gb + (size_t)((K0 + 0) * 2) * HW);
    uint4 wv1 = *(const uint4*)(gb + (size_t)((K0 + 1) * 2) * HW);
    uint4 wv2 = *(const uint4*)(gb + (size_t)((K0 + 2) * 2) * HW);
    if constexpr (D == 1) {
      tapfma<7>(y, W[0], W[1], wv0);
      tapfma<0>(y, W[1], W[1], wv1);
      tapfma<1>(y, W[1], W[2], wv2);
    } else if constexpr (D == 6) {
      tapfma<2>(y, W[0], W[1], wv0);
      tapfma<0>(y, W[1], W[1], wv1);
      tapfma<6>(y, W[1], W[2], wv2);
    } else if constexpr (D == 12) {
      tapfma<4>(y, W[0], W[1], wv0);
      tapfma<0>(y, W[2], W[2], wv1);
      tapfma<4>(y, W[3], W[4], wv2);
    } else if constexpr (D == 24) {
      tapfma<0>(y, W[0], W[0], wv0);
      tapfma<0>(y, W[1], W[1], wv1);
      tapfma<0>(y, W[2], W[2], wv2);
    } else {  // 36
      tapfma<4>(y, W[0], W[1], wv0);
      tapfma<0>(y, W[2], W[2], wv1);
      tapfma<4>(y, W[3], W[4], wv2);
    }
  }
}

// all 5 branches + identity for one 8-px half; straight-line, compile-time idx
__device__ __forceinline__ void half8(float* y, const unsigned short* __restrict__ z,
                                      unsigned chsl, unsigned guard,
                                      const unsigned short* __restrict__ gb,
                                      int h, int w0, unsigned ph) {
  {  // identity (slab 0, always valid)
    uint4 v = *(const uint4*)(z + chsl + ph);
    const unsigned short* u = (const unsigned short*)&v;
#pragma unroll
    for (int j = 0; j < 8; ++j) y[j] = bf2f(u[j]);
  }
  branch8<1, 1>(y, z, chsl + 512u * ZSLAB, guard, gb, h, w0);
  branch8<2, 6>(y, z, chsl + 1024u * ZSLAB, guard, gb, h, w0);
  branch8<3, 12>(y, z, chsl + 1536u * ZSLAB, guard, gb, h, w0);
  branch8<4, 24>(y, z, chsl + 2048u * ZSLAB, guard, gb, h, w0);
  branch8<5, 36>(y, z, chsl + 2560u * ZSLAB, guard, gb, h, w0);
}

// ---------- init: xpose into tiled layout | weight repack (tiled Wsb) ----------
// xb tiled: [144 tiles(128 rows)][32 chunks(8 k)][128 rows][8] shorts
__global__ __launch_bounds__(256) void init_all(const float* __restrict__ x,
                                                const float* __restrict__ Ws,
                                                const float* __restrict__ Wc,
                                                unsigned short* __restrict__ xb,
                                                unsigned short* __restrict__ Wsb,
                                                unsigned short* __restrict__ Wcb) {
  __shared__ float tile[64][65];
  int id = blockIdx.x;
  int t = threadIdx.x;
  if (id < 1152) {  // xpose
    int bx = id % 144, by = (id / 144) % 4, n = id / 576;
    int p0 = bx * 64, ci0 = by * 64;
    int cl = t & 63, q = t >> 6;
#pragma unroll
    for (int i = 0; i < 16; ++i) {
      int cir = q + i * 4;
      tile[cir][cl] = x[((size_t)(n * 256 + ci0 + cir)) * HW + p0 + cl];
    }
    __syncthreads();
    // write: lane = row, 2 uint4 (=2 chunks of 8 ch) per thread, contiguous
    int R = n * HW + p0 + cl;
    int Rt = R >> 7, Rl = R & 127;
#pragma unroll
    for (int i = 0; i < 2; ++i) {
      int cloc = q * 2 + i;  // chunk-local 0..7
      unsigned rr[4];
#pragma unroll
      for (int jj = 0; jj < 4; ++jj) {
        unsigned short a = f2bf(tile[cloc * 8 + jj * 2][cl]);
        unsigned short b = f2bf(tile[cloc * 8 + jj * 2 + 1][cl]);
        rr[jj] = (unsigned)a | ((unsigned)b << 16);
      }
      *(uint4*)(xb + (size_t)Rt * XTILE + (by * 8 + cloc) * 1024 + Rl * 8) =
          make_uint4(rr[0], rr[1], rr[2], rr[3]);
    }
  } else {  // weight repack
    int u = (id - 1152) * 256 + t;
    if (u < 393216) {  // Wsb tiled: [12 tiles][32 chunks][128 rows][8]
      int r = u >> 8, k = u & 255;
      Wsb[(size_t)(r >> 7) * XTILE + (k >> 3) * 1024 + (r & 127) * 8 + (k & 7)] =
          f2bf(Ws[(size_t)(r & 255) * 1536 + (r >> 8) * 256 + k]);
    } else {
      int v = u - 393216;
      if (v < 110592) {
        int co = v / 2304, rr = v % 2304;
        int j = rr >> 8, ci = rr & 255;
        Wcb[v] = (co < 45) ? f2bf(Wc[(size_t)co * 2304 + ci * 9 + j]) : (unsigned short)0;
      }
    }
  }
}

// ---------- gemms: gemm_g first (288 blocks) | gemm_z (contiguous DMA) ----------
__global__ __launch_bounds__(256) void gemms(const unsigned short* __restrict__ xb,
                                             const unsigned short* __restrict__ Wsb,
                                             const unsigned short* __restrict__ Wcb,
                                             unsigned short* __restrict__ z,
                                             unsigned short* __restrict__ gsmb) {
  __shared__ unsigned short smem[16384];  // 32KB
  int id = blockIdx.x;
  int t = threadIdx.x;
  int wid = t >> 6, lane = t & 63;
  int q = lane >> 4, ln = lane & 15;

  if (id < 288) {
    // ===== gemm_g: BM=64 BN=48 BK=64 (36 steps), reg-prefetch, fused softmax =====
    unsigned short* As = smem;          // 8 kq x 64 mm x uint4 = 8KB
    unsigned short* Bs = smem + 4096;   // 8 kq x 48 nn x uint4 = 6KB
    int m0 = id * 64;
    int mm = t >> 2, kq = t & 3;
    int m = m0 + mm;
    int img = m / HW, p = m % HW;
    int h = p / 96, w = p % 96;
    int mbase = img * HW;
    int nn = t >> 2;  // for Bs (t<192)
    f32x4 acc[3] = {};
    uint4 aA0, aA1, aB0, aB1;

    // prefetch step 0 (tap j=0 -> dy=-1,dx=-1; chunks kq, kq+4 of tile)
    {
      int hh = h - 1, ww = w - 1;
      bool valid = ((unsigned)hh < 96u) & ((unsigned)ww < 96u);
      int R = mbase + hh * 96 + ww;
      const unsigned short* pa =
          xb + (long)(R >> 7) * XTILE + kq * 1024 + (R & 127) * 8;
      aA0 = valid ? *(const uint4*)pa : make_uint4(0, 0, 0, 0);
      aA1 = valid ? *(const uint4*)(pa + 4096) : make_uint4(0, 0, 0, 0);
      if (t < 192) {
        const unsigned short* pb = Wcb + (size_t)nn * 2304 + kq * 8;
        aB0 = *(const uint4*)pb;
        aB1 = *(const uint4*)(pb + 32);
      }
    }

    for (int s = 0; s < 36; ++s) {
      ((uint4*)As)[kq * 64 + mm] = aA0;
      ((uint4*)As)[(kq + 4) * 64 + mm] = aA1;
      if (t < 192) {
        ((uint4*)Bs)[kq * 48 + nn] = aB0;
        ((uint4*)Bs)[(kq + 4) * 48 + nn] = aB1;
      }
      __syncthreads();
      if (s + 1 < 36) {  // prefetch next step; consumed next iteration
        int s1 = s + 1;
        int j = s1 >> 2;
        int hh = h + j / 3 - 1, ww = w + j % 3 - 1;
        bool valid = ((unsigned)hh < 96u) & ((unsigned)ww < 96u);
        int R = mbase + hh * 96 + ww;
        const unsigned short* pa = xb + (long)(R >> 7) * XTILE +
                                   ((s1 & 3) * 8 + kq) * 1024 + (R & 127) * 8;
        aA0 = valid ? *(const uint4*)pa : make_uint4(0, 0, 0, 0);
        aA1 = valid ? *(const uint4*)(pa + 4096) : make_uint4(0, 0, 0, 0);
        if (t < 192) {
          const unsigned short* pb = Wcb + (size_t)nn * 2304 + s1 * 64 + kq * 8;
          aB0 = *(const uint4*)pb;
          aB1 = *(const uint4*)(pb + 32);
        }
      }
#pragma unroll
      for (int kk = 0; kk < 2; ++kk) {
        bf16x8 a = ((const bf16x8*)As)[(kk * 4 + q) * 64 + wid * 16 + ln];
#pragma unroll
        for (int fn = 0; fn < 3; ++fn) {
          bf16x8 b = ((const bf16x8*)Bs)[(kk * 4 + q) * 48 + fn * 16 + ln];
          acc[fn] = __builtin_amdgcn_mfma_f32_16x16x32_bf16(a, b, acc[fn], 0, 0, 0);
        }
      }
      __syncthreads();
    }

    // fused softmax epilogue: acc -> LDS f32 [64px][49], then 64 threads softmax
    float* LDSf = (float*)smem;  // 64*49*4 = 12544B
#pragma unroll
    for (int fn = 0; fn < 3; ++fn)
#pragma unroll
      for (int r = 0; r < 4; ++r)
        LDSf[(wid * 16 + q * 4 + r) * 49 + fn * 16 + ln] = acc[fn][r];
    __syncthreads();
    if (t < 64) {
      const float* row = LDSf + t * 49;
      int mg = m0 + t;
      int img2 = mg / HW, p2 = mg - img2 * HW;
      for (int grp = 0; grp < 5; ++grp) {
        float v[9], mx = -1e30f;
#pragma unroll
        for (int k = 0; k < 9; ++k) { v[k] = row[grp * 9 + k]; mx = fmaxf(mx, v[k]); }
        float sum = 0.f;
#pragma unroll
        for (int k = 0; k < 9; ++k) { v[k] = __expf(v[k] - mx); sum += v[k]; }
        float inv = 1.f / sum;
#pragma unroll
        for (int k = 0; k < 9; ++k) {
          int col = grp * 9 + k;
          gsmb[((size_t)(col * 2 + img2)) * HW + p2] = f2bf(v[k] * inv);
        }
      }
    }
  } else {
    // ===== gemm_z: 128x128, K=256, double-buffered FULLY-CONTIGUOUS DMA =====
    int zid = id - 288;
    int mt = zid % 144, ct = zid / 144;
    int m0 = mt * 128, c0 = ct * 128;
    int wm = (wid >> 1) * 64, wn = (wid & 1) * 64;
    bool isB = wid >= 2;
    // tiled source: per K-step the 8KB stage region is linear
    const unsigned short* gsrc =
        (isB ? Wsb + (size_t)ct * XTILE : xb + (size_t)mt * XTILE) + lane * 8;
    unsigned short* lb = smem + (isB ? 8192 : 0);
    int ow = (wid & 1) * 4;  // op offset: waves {0,2}->0..3, {1,3}->4..7
    f32x4 acc[4][4] = {};

    // stage step 0 into buffer 0
#pragma unroll
    for (int kq = 0; kq < 4; ++kq)
      async16(gsrc + (ow + kq) * 512, lb + (ow + kq) * 512);
    __syncthreads();

    for (int s = 0; s < 8; ++s) {
      int cur = s & 1, nxt = cur ^ 1;
      if (s < 7) {  // issue next-step DMA; drained by end-of-iter barrier
#pragma unroll
        for (int kq = 0; kq < 4; ++kq)
          async16(gsrc + (s + 1) * 4096 + (ow + kq) * 512,
                  lb + nxt * 4096 + (ow + kq) * 512);
      }
      const unsigned short* Asc = smem + cur * 4096;
      const unsigned short* Bsc = smem + 8192 + cur * 4096;
      bf16x8 a[4], b[4];
#pragma unroll
      for (int f = 0; f < 4; ++f) {
        a[f] = ((const bf16x8*)Asc)[q * 128 + wm + f * 16 + ln];
        b[f] = ((const bf16x8*)Bsc)[q * 128 + wn + f * 16 + ln];
      }
#pragma unroll
      for (int fm = 0; fm < 4; ++fm)
#pragma unroll
        for (int fn = 0; fn < 4; ++fn)
          acc[fm][fn] = __builtin_amdgcn_mfma_f32_16x16x32_bf16(a[fm], b[fn], acc[fm][fn], 0, 0, 0);
      __syncthreads();
    }

    // epilogue: packed z; per-channel 256B contiguous line-aligned runs
    int sl = c0 >> 8, cb = c0 & 255;
    int img = m0 / HW;
    int pbase = m0 - img * HW;
#pragma unroll
    for (int fm = 0; fm < 4; ++fm) {
      int p = pbase + wm + fm * 16 + q * 4;
#pragma unroll
      for (int fn = 0; fn < 4; ++fn) {
        int ch = cb + wn + fn * 16 + ln;
        size_t slab = ((size_t)(sl * 256 + ch) * 2 + img) * ZSLAB;
        unsigned lo = (unsigned)f2bf(acc[fm][fn][0]) | ((unsigned)f2bf(acc[fm][fn][1]) << 16);
        unsigned hi = (unsigned)f2bf(acc[fm][fn][2]) | ((unsigned)f2bf(acc[fm][fn][3]) << 16);
        *(uint2*)(z + slab + p) = make_uint2(lo, hi);
      }
    }
  }
}

// ---------- accum: flat 128-thr blocks, 16px/thread, guard-redirect masking ----
// 2304 blocks = 9 blocks/CU x 2 waves = 18 waves/CU, single cohort.
// Two straight-line 8-px halves with SEPARATE named register arrays (no
// runtime-indexed local array -> no scratch; that was round-5's 1.8GB bug).
__global__ __launch_bounds__(128, 5) void accum_chw(const unsigned short* __restrict__ z,
                                                    const unsigned short* __restrict__ gsmb,
                                                    float* __restrict__ yacc,
                                                    float* __restrict__ stats,
                                                    unsigned guard) {
  int cid = blockIdx.x * 128 + threadIdx.x;
  int img = cid >= 147456;
  int rem = cid - img * 147456;
  int ch = rem / 576;             // 576 chunks (of 16px) per (img,ch); 576%64==0
  int pc = rem - ch * 576;
  int h = pc / 6;
  int w16 = (pc - h * 6) * 16;
  int p0 = h * 96 + w16;

  unsigned chsl = (unsigned)(ch * 2 + img) * ZSLAB;
  const unsigned short* gb0 = gsmb + (size_t)img * HW + p0;

  float yl[8], yh[8];
  half8(yl, z, chsl, guard, gb0, h, w16, (unsigned)p0);
  half8(yh, z, chsl, guard, gb0 + 8, h, w16 + 8, (unsigned)(p0 + 8));

  size_t ybase = ((size_t)(img * 256 + ch)) * HW + p0;
  *(float4*)(yacc + ybase) = make_float4(yl[0], yl[1], yl[2], yl[3]);
  *(float4*)(yacc + ybase + 4) = make_float4(yl[4], yl[5], yl[6], yl[7]);
  *(float4*)(yacc + ybase + 8) = make_float4(yh[0], yh[1], yh[2], yh[3]);
  *(float4*)(yacc + ybase + 12) = make_float4(yh[4], yh[5], yh[6], yh[7]);

  float s1 = 0.f, s2 = 0.f;
#pragma unroll
  for (int j = 0; j < 8; ++j) {
    s1 += yl[j] + yh[j];
    s2 += yl[j] * yl[j] + yh[j] * yh[j];
  }
#pragma unroll
  for (int off = 1; off <= 32; off <<= 1) {
    s1 += __shfl_xor(s1, off);
    s2 += __shfl_xor(s2, off);
  }
  if ((threadIdx.x & 63) == 0) {  // ch is wave-uniform
    atomicAdd(&stats[ch], s1);
    atomicAdd(&stats[256 + ch], s2);
  }
}

// ---------- bn: elementwise on CHW ----------
__global__ __launch_bounds__(256) void bn_apply(const float* __restrict__ yacc,
                                                const float* __restrict__ stats,
                                                const float* __restrict__ gamma,
                                                const float* __restrict__ beta,
                                                float* __restrict__ out) {
  int q = blockIdx.x * 256 + threadIdx.x;
  int ch = (q / 2304) & 255;
  const float inv_cnt = 1.f / 18432.f;
  float mean = stats[ch] * inv_cnt;
  float var = stats[256 + ch] * inv_cnt - mean * mean;
  float sc = rsqrtf(var + 1e-5f) * gamma[ch];
  float sh = beta[ch] - mean * sc;
  float4 v = *(const float4*)(yacc + (size_t)q * 4);
  float4 o = make_float4(v.x * sc + sh, v.y * sc + sh, v.z * sc + sh, v.w * sc + sh);
  *(float4*)(out + (size_t)q * 4) = o;
}

extern "C" void kernel_launch(void* const* d_in, const int* in_sizes, int n_in,
                              void* d_out, int out_size, void* d_ws, size_t ws_size,
                              hipStream_t stream) {
  const float* x = (const float*)d_in[0];
  const float* Wc = (const float*)d_in[1];
  const float* Ws = (const float*)d_in[2];
  const float* gamma = (const float*)d_in[3];
  const float* beta = (const float*)d_in[4];
  float* out = (float*)d_out;

  unsigned short* xb = (unsigned short*)d_ws;   // 4718592 us (tiled)
  unsigned short* Wsb = xb + 4718592;           // 393216 us  (tiled)
  unsigned short* Wcb = Wsb + 393216;           // 110592 us
  unsigned short* gsmb = Wcb + 110592;          // 829440 us   [45col][2img][9216]
  unsigned short* z = gsmb + 829440;            // 28311552 us [6][256][2][9216] packed
  float* yacc = (float*)(z + 28311552);         // 4718592 f32 [img][ch][p]
  float* stats = yacc + 4718592;                // 512 f32
  // zero guard (128 shorts) directly after stats; index relative to z:
  const unsigned guard_idx = 28311552u + 9437184u + 1024u;  // shorts

  hipMemsetAsync(stats, 0, 512 * sizeof(float) + 256, stream);
  init_all<<<3120, 256, 0, stream>>>(x, Ws, Wc, xb, Wsb, Wcb);
  gemms<<<2016, 256, 0, stream>>>(xb, Wsb, Wcb, z, gsmb);
  accum_chw<<<2304, 128, 0, stream>>>(z, gsmb, yacc, stats, guard_idx);
  bn_apply<<<4608, 256, 0, stream>>>(yacc, stats, gamma, beta, out);
}

// Round 7
// 202.789 us; speedup vs baseline: 3.4367x; 3.4367x over previous
//
#include <hip/hip_runtime.h>

typedef __bf16 bf16x8 __attribute__((ext_vector_type(8)));
typedef float f32x4 __attribute__((ext_vector_type(4)));

#define HW 9216
#define ZSLAB 9216   // packed 96*96 elems per (sl,ch,img) slab — no pads
#define XTILE 32768  // shorts per xb/Wsb tile: 32 chunks x 128 rows x 8 elems

__device__ __forceinline__ unsigned short f2bf(float f) {
  unsigned u = __float_as_uint(f);
  unsigned r = (u + 0x7FFFu + ((u >> 16) & 1u)) >> 16;
  return (unsigned short)r;
}
__device__ __forceinline__ float bf2f(unsigned short h) {
  return __uint_as_float(((unsigned)h) << 16);
}

__device__ __forceinline__ void async16(const unsigned short* g, unsigned short* l) {
  __builtin_amdgcn_global_load_lds(
      (const __attribute__((address_space(1))) unsigned int*)g,
      (__attribute__((address_space(3))) unsigned int*)l, 16, 0, 0);
}

// y[j] += w[j] * z[O+j], z drawn from the 16-elem window {lo,hi}, O compile-time
template <int O>
__device__ __forceinline__ void tapfma(float* y, uint4 lo, uint4 hi, uint4 wv) {
  const unsigned short* lu = (const unsigned short*)&lo;
  const unsigned short* hu = (const unsigned short*)&hi;
  const unsigned short* wu = (const unsigned short*)&wv;
#pragma unroll
  for (int j = 0; j < 8; ++j) {
    unsigned short zz = (O + j < 8) ? lu[O + j] : hu[O + j - 8];
    y[j] += bf2f(wu[j]) * bf2f(zz);
  }
}

// guarded 16B window load: invalid -> zeroed guard region (exact-zero contrib)
__device__ __forceinline__ uint4 gload(const unsigned short* __restrict__ z,
                                       bool v, unsigned idx, unsigned guard) {
  return *(const uint4*)(z + (v ? idx : guard));
}

// one 9-tap branch on packed z, 8 px at w0. Union windows shared across the
// 3 taps of each row; guard-redirect masking; ALL locals scalar (no arrays).
template <int B, int D>
__device__ __forceinline__ void branchU(float* y, const unsigned short* __restrict__ z,
                                        unsigned slab, unsigned guard,
                                        const unsigned short* __restrict__ gb,
                                        int h, int w0) {
  // column validity, scalar, hoisted across rows
  const bool cmv = ((unsigned)(w0 - ((D == 1 || D == 6) ? 8 : (D == 12 ? 16 : (D == 24 ? 24 : 40)))) <= 88u);
  const bool cm2v = ((unsigned)(w0 - ((D == 12) ? 8 : 32)) <= 88u);   // D12/D36 only
  const bool cpv = ((unsigned)(w0 + ((D == 1 || D == 6) ? 8 : (D == 12 ? 16 : (D == 24 ? 24 : 40)))) <= 88u);
  const bool cp2v = ((unsigned)(w0 + ((D == 12) ? 8 : 32)) <= 88u);   // D12/D36 only

#pragma unroll
  for (int r = 0; r < 3; ++r) {
    int hh = h + (r - 1) * D;
    bool rv = ((unsigned)hh < 96u);
    unsigned rb = slab + (unsigned)(hh * 96);
    const int K0 = (B - 1) * 9 + r * 3;
    uint4 wv0 = *(const uint4*)(gb + (size_t)((K0 + 0) * 2) * HW);
    uint4 wv1 = *(const uint4*)(gb + (size_t)((K0 + 1) * 2) * HW);
    uint4 wv2 = *(const uint4*)(gb + (size_t)((K0 + 2) * 2) * HW);
    if constexpr (D == 1 || D == 6) {
      uint4 Wm = gload(z, rv && cmv, rb + (unsigned)(w0 - 8), guard);
      uint4 W0 = gload(z, rv, rb + (unsigned)w0, guard);
      uint4 Wp = gload(z, rv && cpv, rb + (unsigned)(w0 + 8), guard);
      if constexpr (D == 1) {
        tapfma<7>(y, Wm, W0, wv0);
        tapfma<0>(y, W0, W0, wv1);
        tapfma<1>(y, W0, Wp, wv2);
      } else {
        tapfma<2>(y, Wm, W0, wv0);
        tapfma<0>(y, W0, W0, wv1);
        tapfma<6>(y, W0, Wp, wv2);
      }
    } else if constexpr (D == 24) {
      uint4 Wm = gload(z, rv && cmv, rb + (unsigned)(w0 - 24), guard);
      uint4 W0 = gload(z, rv, rb + (unsigned)w0, guard);
      uint4 Wp = gload(z, rv && cpv, rb + (unsigned)(w0 + 24), guard);
      tapfma<0>(y, Wm, Wm, wv0);
      tapfma<0>(y, W0, W0, wv1);
      tapfma<0>(y, Wp, Wp, wv2);
    } else {  // D == 12 or 36; outer taps use O=4 with two windows each
      constexpr int co = (D == 12) ? 16 : 40;
      constexpr int ci = (D == 12) ? 8 : 32;
      uint4 Wa = gload(z, rv && cmv, rb + (unsigned)(w0 - co), guard);
      uint4 Wb = gload(z, rv && cm2v, rb + (unsigned)(w0 - ci), guard);
      uint4 W0 = gload(z, rv, rb + (unsigned)w0, guard);
      uint4 Wc = gload(z, rv && cp2v, rb + (unsigned)(w0 + ci), guard);
      uint4 Wd = gload(z, rv && cpv, rb + (unsigned)(w0 + co), guard);
      tapfma<4>(y, Wa, Wb, wv0);
      tapfma<0>(y, W0, W0, wv1);
      tapfma<4>(y, Wc, Wd, wv2);
    }
  }
}

// ---------- init: xpose into tiled layout | weight repack (tiled Wsb) ----------
// xb tiled: [144 tiles(128 rows)][32 chunks(8 k)][128 rows][8] shorts
__global__ __launch_bounds__(256) void init_all(const float* __restrict__ x,
                                                const float* __restrict__ Ws,
                                                const float* __restrict__ Wc,
                                                unsigned short* __restrict__ xb,
                                                unsigned short* __restrict__ Wsb,
                                                unsigned short* __restrict__ Wcb) {
  __shared__ float tile[64][65];
  int id = blockIdx.x;
  int t = threadIdx.x;
  if (id < 1152) {  // xpose
    int bx = id % 144, by = (id / 144) % 4, n = id / 576;
    int p0 = bx * 64, ci0 = by * 64;
    int cl = t & 63, q = t >> 6;
#pragma unroll
    for (int i = 0; i < 16; ++i) {
      int cir = q + i * 4;
      tile[cir][cl] = x[((size_t)(n * 256 + ci0 + cir)) * HW + p0 + cl];
    }
    __syncthreads();
    // write: lane = row, 2 uint4 (=2 chunks of 8 ch) per thread, contiguous
    int R = n * HW + p0 + cl;
    int Rt = R >> 7, Rl = R & 127;
#pragma unroll
    for (int i = 0; i < 2; ++i) {
      int cloc = q * 2 + i;  // chunk-local 0..7
      unsigned rr[4];
#pragma unroll
      for (int jj = 0; jj < 4; ++jj) {
        unsigned short a = f2bf(tile[cloc * 8 + jj * 2][cl]);
        unsigned short b = f2bf(tile[cloc * 8 + jj * 2 + 1][cl]);
        rr[jj] = (unsigned)a | ((unsigned)b << 16);
      }
      *(uint4*)(xb + (size_t)Rt * XTILE + (by * 8 + cloc) * 1024 + Rl * 8) =
          make_uint4(rr[0], rr[1], rr[2], rr[3]);
    }
  } else {  // weight repack
    int u = (id - 1152) * 256 + t;
    if (u < 393216) {  // Wsb tiled: [12 tiles][32 chunks][128 rows][8]
      int r = u >> 8, k = u & 255;
      Wsb[(size_t)(r >> 7) * XTILE + (k >> 3) * 1024 + (r & 127) * 8 + (k & 7)] =
          f2bf(Ws[(size_t)(r & 255) * 1536 + (r >> 8) * 256 + k]);
    } else {
      int v = u - 393216;
      if (v < 110592) {
        int co = v / 2304, rr = v % 2304;
        int j = rr >> 8, ci = rr & 255;
        Wcb[v] = (co < 45) ? f2bf(Wc[(size_t)co * 2304 + ci * 9 + j]) : (unsigned short)0;
      }
    }
  }
}

// ---------- gemms: gemm_g first (288 blocks) | gemm_z (contiguous DMA) ----------
__global__ __launch_bounds__(256) void gemms(const unsigned short* __restrict__ xb,
                                             const unsigned short* __restrict__ Wsb,
                                             const unsigned short* __restrict__ Wcb,
                                             unsigned short* __restrict__ z,
                                             unsigned short* __restrict__ gsmb) {
  __shared__ unsigned short smem[16384];  // 32KB
  int id = blockIdx.x;
  int t = threadIdx.x;
  int wid = t >> 6, lane = t & 63;
  int q = lane >> 4, ln = lane & 15;

  if (id < 288) {
    // ===== gemm_g: BM=64 BN=48 BK=64 (36 steps), reg-prefetch, fused softmax =====
    unsigned short* As = smem;          // 8 kq x 64 mm x uint4 = 8KB
    unsigned short* Bs = smem + 4096;   // 8 kq x 48 nn x uint4 = 6KB
    int m0 = id * 64;
    int mm = t >> 2, kq = t & 3;
    int m = m0 + mm;
    int img = m / HW, p = m % HW;
    int h = p / 96, w = p % 96;
    int mbase = img * HW;
    int nn = t >> 2;  // for Bs (t<192)
    f32x4 acc[3] = {};
    uint4 aA0, aA1, aB0, aB1;

    // prefetch step 0 (tap j=0 -> dy=-1,dx=-1; chunks kq, kq+4 of tile)
    {
      int hh = h - 1, ww = w - 1;
      bool valid = ((unsigned)hh < 96u) & ((unsigned)ww < 96u);
      int R = mbase + hh * 96 + ww;
      const unsigned short* pa =
          xb + (long)(R >> 7) * XTILE + kq * 1024 + (R & 127) * 8;
      aA0 = valid ? *(const uint4*)pa : make_uint4(0, 0, 0, 0);
      aA1 = valid ? *(const uint4*)(pa + 4096) : make_uint4(0, 0, 0, 0);
      if (t < 192) {
        const unsigned short* pb = Wcb + (size_t)nn * 2304 + kq * 8;
        aB0 = *(const uint4*)pb;
        aB1 = *(const uint4*)(pb + 32);
      }
    }

    for (int s = 0; s < 36; ++s) {
      ((uint4*)As)[kq * 64 + mm] = aA0;
      ((uint4*)As)[(kq + 4) * 64 + mm] = aA1;
      if (t < 192) {
        ((uint4*)Bs)[kq * 48 + nn] = aB0;
        ((uint4*)Bs)[(kq + 4) * 48 + nn] = aB1;
      }
      __syncthreads();
      if (s + 1 < 36) {  // prefetch next step; consumed next iteration
        int s1 = s + 1;
        int j = s1 >> 2;
        int hh = h + j / 3 - 1, ww = w + j % 3 - 1;
        bool valid = ((unsigned)hh < 96u) & ((unsigned)ww < 96u);
        int R = mbase + hh * 96 + ww;
        const unsigned short* pa = xb + (long)(R >> 7) * XTILE +
                                   ((s1 & 3) * 8 + kq) * 1024 + (R & 127) * 8;
        aA0 = valid ? *(const uint4*)pa : make_uint4(0, 0, 0, 0);
        aA1 = valid ? *(const uint4*)(pa + 4096) : make_uint4(0, 0, 0, 0);
        if (t < 192) {
          const unsigned short* pb = Wcb + (size_t)nn * 2304 + s1 * 64 + kq * 8;
          aB0 = *(const uint4*)pb;
          aB1 = *(const uint4*)(pb + 32);
        }
      }
#pragma unroll
      for (int kk = 0; kk < 2; ++kk) {
        bf16x8 a = ((const bf16x8*)As)[(kk * 4 + q) * 64 + wid * 16 + ln];
#pragma unroll
        for (int fn = 0; fn < 3; ++fn) {
          bf16x8 b = ((const bf16x8*)Bs)[(kk * 4 + q) * 48 + fn * 16 + ln];
          acc[fn] = __builtin_amdgcn_mfma_f32_16x16x32_bf16(a, b, acc[fn], 0, 0, 0);
        }
      }
      __syncthreads();
    }

    // fused softmax epilogue: acc -> LDS f32 [64px][49], then 64 threads softmax
    float* LDSf = (float*)smem;  // 64*49*4 = 12544B
#pragma unroll
    for (int fn = 0; fn < 3; ++fn)
#pragma unroll
      for (int r = 0; r < 4; ++r)
        LDSf[(wid * 16 + q * 4 + r) * 49 + fn * 16 + ln] = acc[fn][r];
    __syncthreads();
    if (t < 64) {
      const float* row = LDSf + t * 49;
      int mg = m0 + t;
      int img2 = mg / HW, p2 = mg - img2 * HW;
      for (int grp = 0; grp < 5; ++grp) {
        float v[9], mx = -1e30f;
#pragma unroll
        for (int k = 0; k < 9; ++k) { v[k] = row[grp * 9 + k]; mx = fmaxf(mx, v[k]); }
        float sum = 0.f;
#pragma unroll
        for (int k = 0; k < 9; ++k) { v[k] = __expf(v[k] - mx); sum += v[k]; }
        float inv = 1.f / sum;
#pragma unroll
        for (int k = 0; k < 9; ++k) {
          int col = grp * 9 + k;
          gsmb[((size_t)(col * 2 + img2)) * HW + p2] = f2bf(v[k] * inv);
        }
      }
    }
  } else {
    // ===== gemm_z: 128x128, K=256, double-buffered FULLY-CONTIGUOUS DMA =====
    int zid = id - 288;
    int mt = zid % 144, ct = zid / 144;
    int m0 = mt * 128, c0 = ct * 128;
    int wm = (wid >> 1) * 64, wn = (wid & 1) * 64;
    bool isB = wid >= 2;
    // tiled source: per K-step the 8KB stage region is linear
    const unsigned short* gsrc =
        (isB ? Wsb + (size_t)ct * XTILE : xb + (size_t)mt * XTILE) + lane * 8;
    unsigned short* lb = smem + (isB ? 8192 : 0);
    int ow = (wid & 1) * 4;  // op offset: waves {0,2}->0..3, {1,3}->4..7
    f32x4 acc[4][4] = {};

    // stage step 0 into buffer 0
#pragma unroll
    for (int kq = 0; kq < 4; ++kq)
      async16(gsrc + (ow + kq) * 512, lb + (ow + kq) * 512);
    __syncthreads();

    for (int s = 0; s < 8; ++s) {
      int cur = s & 1, nxt = cur ^ 1;
      if (s < 7) {  // issue next-step DMA; drained by end-of-iter barrier
#pragma unroll
        for (int kq = 0; kq < 4; ++kq)
          async16(gsrc + (s + 1) * 4096 + (ow + kq) * 512,
                  lb + nxt * 4096 + (ow + kq) * 512);
      }
      const unsigned short* Asc = smem + cur * 4096;
      const unsigned short* Bsc = smem + 8192 + cur * 4096;
      bf16x8 a[4], b[4];
#pragma unroll
      for (int f = 0; f < 4; ++f) {
        a[f] = ((const bf16x8*)Asc)[q * 128 + wm + f * 16 + ln];
        b[f] = ((const bf16x8*)Bsc)[q * 128 + wn + f * 16 + ln];
      }
#pragma unroll
      for (int fm = 0; fm < 4; ++fm)
#pragma unroll
        for (int fn = 0; fn < 4; ++fn)
          acc[fm][fn] = __builtin_amdgcn_mfma_f32_16x16x32_bf16(a[fm], b[fn], acc[fm][fn], 0, 0, 0);
      __syncthreads();
    }

    // epilogue: packed z; per-channel 256B contiguous line-aligned runs
    int sl = c0 >> 8, cb = c0 & 255;
    int img = m0 / HW;
    int pbase = m0 - img * HW;
#pragma unroll
    for (int fm = 0; fm < 4; ++fm) {
      int p = pbase + wm + fm * 16 + q * 4;
#pragma unroll
      for (int fn = 0; fn < 4; ++fn) {
        int ch = cb + wn + fn * 16 + ln;
        size_t slab = ((size_t)(sl * 256 + ch) * 2 + img) * ZSLAB;
        unsigned lo = (unsigned)f2bf(acc[fm][fn][0]) | ((unsigned)f2bf(acc[fm][fn][1]) << 16);
        unsigned hi = (unsigned)f2bf(acc[fm][fn][2]) | ((unsigned)f2bf(acc[fm][fn][3]) << 16);
        *(uint2*)(z + slab + p) = make_uint2(lo, hi);
      }
    }
  }
}

// ---------- accum: 8 px/thread, scalar-only, union windows, guard-redirect ----
// 2304 blocks x 256 thr (4 waves): 9 blocks/CU, 8 resident (cohort 1.125).
// NO min-waves launch bound (round-5/6's forced-occupancy spill bug).
__global__ __launch_bounds__(256) void accum_chw(const unsigned short* __restrict__ z,
                                                 const unsigned short* __restrict__ gsmb,
                                                 float* __restrict__ yacc,
                                                 float* __restrict__ stats,
                                                 unsigned guard) {
  int cid = blockIdx.x * 256 + threadIdx.x;   // 8-px chunk id, 589824 total
  int img = cid >= 294912;
  int rem = cid - img * 294912;
  int ch = rem / 1152;            // 1152 chunks per (img,ch); 1152%64==0
  int pc = rem - ch * 1152;
  int h = pc / 12;
  int w0 = (pc - h * 12) * 8;
  int p0 = h * 96 + w0;

  unsigned chsl = (unsigned)(ch * 2 + img) * ZSLAB;
  const unsigned short* gb = gsmb + (size_t)img * HW + p0;

  float y[8];
  {  // identity (slab 0, always valid)
    uint4 v = *(const uint4*)(z + chsl + (unsigned)p0);
    const unsigned short* u = (const unsigned short*)&v;
#pragma unroll
    for (int j = 0; j < 8; ++j) y[j] = bf2f(u[j]);
  }
  branchU<1, 1>(y, z, chsl + 512u * ZSLAB, guard, gb, h, w0);
  branchU<2, 6>(y, z, chsl + 1024u * ZSLAB, guard, gb, h, w0);
  branchU<3, 12>(y, z, chsl + 1536u * ZSLAB, guard, gb, h, w0);
  branchU<4, 24>(y, z, chsl + 2048u * ZSLAB, guard, gb, h, w0);
  branchU<5, 36>(y, z, chsl + 2560u * ZSLAB, guard, gb, h, w0);

  size_t ybase = ((size_t)(img * 256 + ch)) * HW + p0;
  *(float4*)(yacc + ybase) = make_float4(y[0], y[1], y[2], y[3]);
  *(float4*)(yacc + ybase + 4) = make_float4(y[4], y[5], y[6], y[7]);

  float s1 = 0.f, s2 = 0.f;
#pragma unroll
  for (int j = 0; j < 8; ++j) { s1 += y[j]; s2 += y[j] * y[j]; }
#pragma unroll
  for (int off = 1; off <= 32; off <<= 1) {
    s1 += __shfl_xor(s1, off);
    s2 += __shfl_xor(s2, off);
  }
  if ((threadIdx.x & 63) == 0) {  // ch is wave-uniform (1152 % 64 == 0)
    atomicAdd(&stats[ch], s1);
    atomicAdd(&stats[256 + ch], s2);
  }
}

// ---------- bn: elementwise on CHW ----------
__global__ __launch_bounds__(256) void bn_apply(const float* __restrict__ yacc,
                                                const float* __restrict__ stats,
                                                const float* __restrict__ gamma,
                                                const float* __restrict__ beta,
                                                float* __restrict__ out) {
  int q = blockIdx.x * 256 + threadIdx.x;
  int ch = (q / 2304) & 255;
  const float inv_cnt = 1.f / 18432.f;
  float mean = stats[ch] * inv_cnt;
  float var = stats[256 + ch] * inv_cnt - mean * mean;
  float sc = rsqrtf(var + 1e-5f) * gamma[ch];
  float sh = beta[ch] - mean * sc;
  float4 v = *(const float4*)(yacc + (size_t)q * 4);
  float4 o = make_float4(v.x * sc + sh, v.y * sc + sh, v.z * sc + sh, v.w * sc + sh);
  *(float4*)(out + (size_t)q * 4) = o;
}

extern "C" void kernel_launch(void* const* d_in, const int* in_sizes, int n_in,
                              void* d_out, int out_size, void* d_ws, size_t ws_size,
                              hipStream_t stream) {
  const float* x = (const float*)d_in[0];
  const float* Wc = (const float*)d_in[1];
  const float* Ws = (const float*)d_in[2];
  const float* gamma = (const float*)d_in[3];
  const float* beta = (const float*)d_in[4];
  float* out = (float*)d_out;

  unsigned short* xb = (unsigned short*)d_ws;   // 4718592 us (tiled)
  unsigned short* Wsb = xb + 4718592;           // 393216 us  (tiled)
  unsigned short* Wcb = Wsb + 393216;           // 110592 us
  unsigned short* gsmb = Wcb + 110592;          // 829440 us   [45col][2img][9216]
  unsigned short* z = gsmb + 829440;            // 28311552 us [6][256][2][9216] packed
  float* yacc = (float*)(z + 28311552);         // 4718592 f32 [img][ch][p]
  float* stats = yacc + 4718592;                // 512 f32
  // zero guard (128 shorts) directly after stats; index relative to z:
  const unsigned guard_idx = 28311552u + 9437184u + 1024u;  // shorts

  hipMemsetAsync(stats, 0, 512 * sizeof(float) + 256, stream);
  init_all<<<3120, 256, 0, stream>>>(x, Ws, Wc, xb, Wsb, Wcb);
  gemms<<<2016, 256, 0, stream>>>(xb, Wsb, Wcb, z, gsmb);
  accum_chw<<<2304, 256, 0, stream>>>(z, gsmb, yacc, stats, guard_idx);
  bn_apply<<<4608, 256, 0, stream>>>(yacc, stats, gamma, beta, out);
}

// Round 8
// 185.878 us; speedup vs baseline: 3.7494x; 1.0910x over previous
//
#include <hip/hip_runtime.h>

typedef __bf16 bf16x8 __attribute__((ext_vector_type(8)));
typedef float f32x4 __attribute__((ext_vector_type(4)));

#define HW 9216
#define ZSLAB 9216   // packed 96*96 elems per (sl,ch,img) slab — no pads
#define XTILE 32768  // shorts per xb/Wsb tile: 32 chunks x 128 rows x 8 elems

__device__ __forceinline__ unsigned short f2bf(float f) {
  unsigned u = __float_as_uint(f);
  unsigned r = (u + 0x7FFFu + ((u >> 16) & 1u)) >> 16;
  return (unsigned short)r;
}
__device__ __forceinline__ float bf2f(unsigned short h) {
  return __uint_as_float(((unsigned)h) << 16);
}

__device__ __forceinline__ void async16(const unsigned short* g, unsigned short* l) {
  __builtin_amdgcn_global_load_lds(
      (const __attribute__((address_space(1))) unsigned int*)g,
      (__attribute__((address_space(3))) unsigned int*)l, 16, 0, 0);
}

// y[j] += w[j] * z[O+j], z drawn from the 16-elem window {lo,hi}, O compile-time
template <int O>
__device__ __forceinline__ void tapfma(float* y, uint4 lo, uint4 hi, uint4 wv) {
  const unsigned short* lu = (const unsigned short*)&lo;
  const unsigned short* hu = (const unsigned short*)&hi;
  const unsigned short* wu = (const unsigned short*)&wv;
#pragma unroll
  for (int j = 0; j < 8; ++j) {
    unsigned short zz = (O + j < 8) ? lu[O + j] : hu[O + j - 8];
    y[j] += bf2f(wu[j]) * bf2f(zz);
  }
}

// guarded 16B window load: invalid -> zeroed guard region (exact-zero contrib)
__device__ __forceinline__ uint4 gload(const unsigned short* __restrict__ z,
                                       bool v, unsigned idx, unsigned guard) {
  return *(const uint4*)(z + (v ? idx : guard));
}

// one 9-tap branch on packed z, 8 px at w0. Union windows shared across the
// 3 taps of each row; guard-redirect masking; ALL locals scalar (no arrays).
// sched_barrier(0) after each row caps the scheduler's pipelining depth so
// VGPR stays low (round-7 lesson: 148 VGPR -> 3 waves/SIMD -> latency-bound).
template <int B, int D>
__device__ __forceinline__ void branchU(float* y, const unsigned short* __restrict__ z,
                                        unsigned slab, unsigned guard,
                                        const unsigned short* __restrict__ gb,
                                        int h, int w0) {
  // column validity, scalar, hoisted across rows
  const bool cmv = ((unsigned)(w0 - ((D == 1 || D == 6) ? 8 : (D == 12 ? 16 : (D == 24 ? 24 : 40)))) <= 88u);
  const bool cm2v = ((unsigned)(w0 - ((D == 12) ? 8 : 32)) <= 88u);   // D12/D36 only
  const bool cpv = ((unsigned)(w0 + ((D == 1 || D == 6) ? 8 : (D == 12 ? 16 : (D == 24 ? 24 : 40)))) <= 88u);
  const bool cp2v = ((unsigned)(w0 + ((D == 12) ? 8 : 32)) <= 88u);   // D12/D36 only

#pragma unroll
  for (int r = 0; r < 3; ++r) {
    int hh = h + (r - 1) * D;
    bool rv = ((unsigned)hh < 96u);
    unsigned rb = slab + (unsigned)(hh * 96);
    const int K0 = (B - 1) * 9 + r * 3;
    uint4 wv0 = *(const uint4*)(gb + (size_t)((K0 + 0) * 2) * HW);
    uint4 wv1 = *(const uint4*)(gb + (size_t)((K0 + 1) * 2) * HW);
    uint4 wv2 = *(const uint4*)(gb + (size_t)((K0 + 2) * 2) * HW);
    if constexpr (D == 1 || D == 6) {
      uint4 Wm = gload(z, rv && cmv, rb + (unsigned)(w0 - 8), guard);
      uint4 W0 = gload(z, rv, rb + (unsigned)w0, guard);
      uint4 Wp = gload(z, rv && cpv, rb + (unsigned)(w0 + 8), guard);
      if constexpr (D == 1) {
        tapfma<7>(y, Wm, W0, wv0);
        tapfma<0>(y, W0, W0, wv1);
        tapfma<1>(y, W0, Wp, wv2);
      } else {
        tapfma<2>(y, Wm, W0, wv0);
        tapfma<0>(y, W0, W0, wv1);
        tapfma<6>(y, W0, Wp, wv2);
      }
    } else if constexpr (D == 24) {
      uint4 Wm = gload(z, rv && cmv, rb + (unsigned)(w0 - 24), guard);
      uint4 W0 = gload(z, rv, rb + (unsigned)w0, guard);
      uint4 Wp = gload(z, rv && cpv, rb + (unsigned)(w0 + 24), guard);
      tapfma<0>(y, Wm, Wm, wv0);
      tapfma<0>(y, W0, W0, wv1);
      tapfma<0>(y, Wp, Wp, wv2);
    } else {  // D == 12 or 36; outer taps use O=4 with two windows each
      constexpr int co = (D == 12) ? 16 : 40;
      constexpr int ci = (D == 12) ? 8 : 32;
      uint4 Wa = gload(z, rv && cmv, rb + (unsigned)(w0 - co), guard);
      uint4 Wb = gload(z, rv && cm2v, rb + (unsigned)(w0 - ci), guard);
      uint4 W0 = gload(z, rv, rb + (unsigned)w0, guard);
      uint4 Wc = gload(z, rv && cp2v, rb + (unsigned)(w0 + ci), guard);
      uint4 Wd = gload(z, rv && cpv, rb + (unsigned)(w0 + co), guard);
      tapfma<4>(y, Wa, Wb, wv0);
      tapfma<0>(y, W0, W0, wv1);
      tapfma<4>(y, Wc, Wd, wv2);
    }
    __builtin_amdgcn_sched_barrier(0);  // cap pipelining depth -> low VGPR
  }
}

// ---------- init: xpose into tiled layout | weight repack (tiled Wsb) ----------
// xb tiled: [144 tiles(128 rows)][32 chunks(8 k)][128 rows][8] shorts
__global__ __launch_bounds__(256) void init_all(const float* __restrict__ x,
                                                const float* __restrict__ Ws,
                                                const float* __restrict__ Wc,
                                                unsigned short* __restrict__ xb,
                                                unsigned short* __restrict__ Wsb,
                                                unsigned short* __restrict__ Wcb) {
  __shared__ float tile[64][65];
  int id = blockIdx.x;
  int t = threadIdx.x;
  if (id < 1152) {  // xpose
    int bx = id % 144, by = (id / 144) % 4, n = id / 576;
    int p0 = bx * 64, ci0 = by * 64;
    int cl = t & 63, q = t >> 6;
#pragma unroll
    for (int i = 0; i < 16; ++i) {
      int cir = q + i * 4;
      tile[cir][cl] = x[((size_t)(n * 256 + ci0 + cir)) * HW + p0 + cl];
    }
    __syncthreads();
    // write: lane = row, 2 uint4 (=2 chunks of 8 ch) per thread, contiguous
    int R = n * HW + p0 + cl;
    int Rt = R >> 7, Rl = R & 127;
#pragma unroll
    for (int i = 0; i < 2; ++i) {
      int cloc = q * 2 + i;  // chunk-local 0..7
      unsigned rr[4];
#pragma unroll
      for (int jj = 0; jj < 4; ++jj) {
        unsigned short a = f2bf(tile[cloc * 8 + jj * 2][cl]);
        unsigned short b = f2bf(tile[cloc * 8 + jj * 2 + 1][cl]);
        rr[jj] = (unsigned)a | ((unsigned)b << 16);
      }
      *(uint4*)(xb + (size_t)Rt * XTILE + (by * 8 + cloc) * 1024 + Rl * 8) =
          make_uint4(rr[0], rr[1], rr[2], rr[3]);
    }
  } else {  // weight repack
    int u = (id - 1152) * 256 + t;
    if (u < 393216) {  // Wsb tiled: [12 tiles][32 chunks][128 rows][8]
      int r = u >> 8, k = u & 255;
      Wsb[(size_t)(r >> 7) * XTILE + (k >> 3) * 1024 + (r & 127) * 8 + (k & 7)] =
          f2bf(Ws[(size_t)(r & 255) * 1536 + (r >> 8) * 256 + k]);
    } else {
      int v = u - 393216;
      if (v < 110592) {
        int co = v / 2304, rr = v % 2304;
        int j = rr >> 8, ci = rr & 255;
        Wcb[v] = (co < 45) ? f2bf(Wc[(size_t)co * 2304 + ci * 9 + j]) : (unsigned short)0;
      }
    }
  }
}

// ---------- gemms: gemm_g first (288 blocks) | gemm_z (contiguous DMA) ----------
__global__ __launch_bounds__(256) void gemms(const unsigned short* __restrict__ xb,
                                             const unsigned short* __restrict__ Wsb,
                                             const unsigned short* __restrict__ Wcb,
                                             unsigned short* __restrict__ z,
                                             unsigned short* __restrict__ gsmb) {
  __shared__ unsigned short smem[16384];  // 32KB
  int id = blockIdx.x;
  int t = threadIdx.x;
  int wid = t >> 6, lane = t & 63;
  int q = lane >> 4, ln = lane & 15;

  if (id < 288) {
    // ===== gemm_g: BM=64 BN=48 BK=64 (36 steps), reg-prefetch, fused softmax =====
    unsigned short* As = smem;          // 8 kq x 64 mm x uint4 = 8KB
    unsigned short* Bs = smem + 4096;   // 8 kq x 48 nn x uint4 = 6KB
    int m0 = id * 64;
    int mm = t >> 2, kq = t & 3;
    int m = m0 + mm;
    int img = m / HW, p = m % HW;
    int h = p / 96, w = p % 96;
    int mbase = img * HW;
    int nn = t >> 2;  // for Bs (t<192)
    f32x4 acc[3] = {};
    uint4 aA0, aA1, aB0, aB1;

    // prefetch step 0 (tap j=0 -> dy=-1,dx=-1; chunks kq, kq+4 of tile)
    {
      int hh = h - 1, ww = w - 1;
      bool valid = ((unsigned)hh < 96u) & ((unsigned)ww < 96u);
      int R = mbase + hh * 96 + ww;
      const unsigned short* pa =
          xb + (long)(R >> 7) * XTILE + kq * 1024 + (R & 127) * 8;
      aA0 = valid ? *(const uint4*)pa : make_uint4(0, 0, 0, 0);
      aA1 = valid ? *(const uint4*)(pa + 4096) : make_uint4(0, 0, 0, 0);
      if (t < 192) {
        const unsigned short* pb = Wcb + (size_t)nn * 2304 + kq * 8;
        aB0 = *(const uint4*)pb;
        aB1 = *(const uint4*)(pb + 32);
      }
    }

    for (int s = 0; s < 36; ++s) {
      ((uint4*)As)[kq * 64 + mm] = aA0;
      ((uint4*)As)[(kq + 4) * 64 + mm] = aA1;
      if (t < 192) {
        ((uint4*)Bs)[kq * 48 + nn] = aB0;
        ((uint4*)Bs)[(kq + 4) * 48 + nn] = aB1;
      }
      __syncthreads();
      if (s + 1 < 36) {  // prefetch next step; consumed next iteration
        int s1 = s + 1;
        int j = s1 >> 2;
        int hh = h + j / 3 - 1, ww = w + j % 3 - 1;
        bool valid = ((unsigned)hh < 96u) & ((unsigned)ww < 96u);
        int R = mbase + hh * 96 + ww;
        const unsigned short* pa = xb + (long)(R >> 7) * XTILE +
                                   ((s1 & 3) * 8 + kq) * 1024 + (R & 127) * 8;
        aA0 = valid ? *(const uint4*)pa : make_uint4(0, 0, 0, 0);
        aA1 = valid ? *(const uint4*)(pa + 4096) : make_uint4(0, 0, 0, 0);
        if (t < 192) {
          const unsigned short* pb = Wcb + (size_t)nn * 2304 + s1 * 64 + kq * 8;
          aB0 = *(const uint4*)pb;
          aB1 = *(const uint4*)(pb + 32);
        }
      }
#pragma unroll
      for (int kk = 0; kk < 2; ++kk) {
        bf16x8 a = ((const bf16x8*)As)[(kk * 4 + q) * 64 + wid * 16 + ln];
#pragma unroll
        for (int fn = 0; fn < 3; ++fn) {
          bf16x8 b = ((const bf16x8*)Bs)[(kk * 4 + q) * 48 + fn * 16 + ln];
          acc[fn] = __builtin_amdgcn_mfma_f32_16x16x32_bf16(a, b, acc[fn], 0, 0, 0);
        }
      }
      __syncthreads();
    }

    // fused softmax epilogue: acc -> LDS f32 [64px][49], then 64 threads softmax
    float* LDSf = (float*)smem;  // 64*49*4 = 12544B
#pragma unroll
    for (int fn = 0; fn < 3; ++fn)
#pragma unroll
      for (int r = 0; r < 4; ++r)
        LDSf[(wid * 16 + q * 4 + r) * 49 + fn * 16 + ln] = acc[fn][r];
    __syncthreads();
    if (t < 64) {
      const float* row = LDSf + t * 49;
      int mg = m0 + t;
      int img2 = mg / HW, p2 = mg - img2 * HW;
      for (int grp = 0; grp < 5; ++grp) {
        float v[9], mx = -1e30f;
#pragma unroll
        for (int k = 0; k < 9; ++k) { v[k] = row[grp * 9 + k]; mx = fmaxf(mx, v[k]); }
        float sum = 0.f;
#pragma unroll
        for (int k = 0; k < 9; ++k) { v[k] = __expf(v[k] - mx); sum += v[k]; }
        float inv = 1.f / sum;
#pragma unroll
        for (int k = 0; k < 9; ++k) {
          int col = grp * 9 + k;
          gsmb[((size_t)(col * 2 + img2)) * HW + p2] = f2bf(v[k] * inv);
        }
      }
    }
  } else {
    // ===== gemm_z: 128x128, K=256, double-buffered FULLY-CONTIGUOUS DMA =====
    int zid = id - 288;
    int mt = zid % 144, ct = zid / 144;
    int m0 = mt * 128, c0 = ct * 128;
    int wm = (wid >> 1) * 64, wn = (wid & 1) * 64;
    bool isB = wid >= 2;
    // tiled source: per K-step the 8KB stage region is linear
    const unsigned short* gsrc =
        (isB ? Wsb + (size_t)ct * XTILE : xb + (size_t)mt * XTILE) + lane * 8;
    unsigned short* lb = smem + (isB ? 8192 : 0);
    int ow = (wid & 1) * 4;  // op offset: waves {0,2}->0..3, {1,3}->4..7
    f32x4 acc[4][4] = {};

    // stage step 0 into buffer 0
#pragma unroll
    for (int kq = 0; kq < 4; ++kq)
      async16(gsrc + (ow + kq) * 512, lb + (ow + kq) * 512);
    __syncthreads();

    for (int s = 0; s < 8; ++s) {
      int cur = s & 1, nxt = cur ^ 1;
      if (s < 7) {  // issue next-step DMA; drained by end-of-iter barrier
#pragma unroll
        for (int kq = 0; kq < 4; ++kq)
          async16(gsrc + (s + 1) * 4096 + (ow + kq) * 512,
                  lb + nxt * 4096 + (ow + kq) * 512);
      }
      const unsigned short* Asc = smem + cur * 4096;
      const unsigned short* Bsc = smem + 8192 + cur * 4096;
      bf16x8 a[4], b[4];
#pragma unroll
      for (int f = 0; f < 4; ++f) {
        a[f] = ((const bf16x8*)Asc)[q * 128 + wm + f * 16 + ln];
        b[f] = ((const bf16x8*)Bsc)[q * 128 + wn + f * 16 + ln];
      }
#pragma unroll
      for (int fm = 0; fm < 4; ++fm)
#pragma unroll
        for (int fn = 0; fn < 4; ++fn)
          acc[fm][fn] = __builtin_amdgcn_mfma_f32_16x16x32_bf16(a[fm], b[fn], acc[fm][fn], 0, 0, 0);
      __syncthreads();
    }

    // epilogue: packed z; per-channel 256B contiguous line-aligned runs
    int sl = c0 >> 8, cb = c0 & 255;
    int img = m0 / HW;
    int pbase = m0 - img * HW;
#pragma unroll
    for (int fm = 0; fm < 4; ++fm) {
      int p = pbase + wm + fm * 16 + q * 4;
#pragma unroll
      for (int fn = 0; fn < 4; ++fn) {
        int ch = cb + wn + fn * 16 + ln;
        size_t slab = ((size_t)(sl * 256 + ch) * 2 + img) * ZSLAB;
        unsigned lo = (unsigned)f2bf(acc[fm][fn][0]) | ((unsigned)f2bf(acc[fm][fn][1]) << 16);
        unsigned hi = (unsigned)f2bf(acc[fm][fn][2]) | ((unsigned)f2bf(acc[fm][fn][3]) << 16);
        *(uint2*)(z + slab + p) = make_uint2(lo, hi);
      }
    }
  }
}

// ---------- accum: 8 px/thread, scalar-only, union windows, guard-redirect ----
// 2304 blocks x 256 thr; per-row sched_barrier keeps VGPR low -> high TLP.
__global__ __launch_bounds__(256) void accum_chw(const unsigned short* __restrict__ z,
                                                 const unsigned short* __restrict__ gsmb,
                                                 float* __restrict__ yacc,
                                                 float* __restrict__ stats,
                                                 unsigned guard) {
  int cid = blockIdx.x * 256 + threadIdx.x;   // 8-px chunk id, 589824 total
  int img = cid >= 294912;
  int rem = cid - img * 294912;
  int ch = rem / 1152;            // 1152 chunks per (img,ch); 1152%64==0
  int pc = rem - ch * 1152;
  int h = pc / 12;
  int w0 = (pc - h * 12) * 8;
  int p0 = h * 96 + w0;

  unsigned chsl = (unsigned)(ch * 2 + img) * ZSLAB;
  const unsigned short* gb = gsmb + (size_t)img * HW + p0;

  float y[8];
  {  // identity (slab 0, always valid)
    uint4 v = *(const uint4*)(z + chsl + (unsigned)p0);
    const unsigned short* u = (const unsigned short*)&v;
#pragma unroll
    for (int j = 0; j < 8; ++j) y[j] = bf2f(u[j]);
  }
  branchU<1, 1>(y, z, chsl + 512u * ZSLAB, guard, gb, h, w0);
  branchU<2, 6>(y, z, chsl + 1024u * ZSLAB, guard, gb, h, w0);
  branchU<3, 12>(y, z, chsl + 1536u * ZSLAB, guard, gb, h, w0);
  branchU<4, 24>(y, z, chsl + 2048u * ZSLAB, guard, gb, h, w0);
  branchU<5, 36>(y, z, chsl + 2560u * ZSLAB, guard, gb, h, w0);

  size_t ybase = ((size_t)(img * 256 + ch)) * HW + p0;
  *(float4*)(yacc + ybase) = make_float4(y[0], y[1], y[2], y[3]);
  *(float4*)(yacc + ybase + 4) = make_float4(y[4], y[5], y[6], y[7]);

  float s1 = 0.f, s2 = 0.f;
#pragma unroll
  for (int j = 0; j < 8; ++j) { s1 += y[j]; s2 += y[j] * y[j]; }
#pragma unroll
  for (int off = 1; off <= 32; off <<= 1) {
    s1 += __shfl_xor(s1, off);
    s2 += __shfl_xor(s2, off);
  }
  if ((threadIdx.x & 63) == 0) {  // ch is wave-uniform (1152 % 64 == 0)
    atomicAdd(&stats[ch], s1);
    atomicAdd(&stats[256 + ch], s2);
  }
}

// ---------- bn: elementwise on CHW ----------
__global__ __launch_bounds__(256) void bn_apply(const float* __restrict__ yacc,
                                                const float* __restrict__ stats,
                                                const float* __restrict__ gamma,
                                                const float* __restrict__ beta,
                                                float* __restrict__ out) {
  int q = blockIdx.x * 256 + threadIdx.x;
  int ch = (q / 2304) & 255;
  const float inv_cnt = 1.f / 18432.f;
  float mean = stats[ch] * inv_cnt;
  float var = stats[256 + ch] * inv_cnt - mean * mean;
  float sc = rsqrtf(var + 1e-5f) * gamma[ch];
  float sh = beta[ch] - mean * sc;
  float4 v = *(const float4*)(yacc + (size_t)q * 4);
  float4 o = make_float4(v.x * sc + sh, v.y * sc + sh, v.z * sc + sh, v.w * sc + sh);
  *(float4*)(out + (size_t)q * 4) = o;
}

extern "C" void kernel_launch(void* const* d_in, const int* in_sizes, int n_in,
                              void* d_out, int out_size, void* d_ws, size_t ws_size,
                              hipStream_t stream) {
  const float* x = (const float*)d_in[0];
  const float* Wc = (const float*)d_in[1];
  const float* Ws = (const float*)d_in[2];
  const float* gamma = (const float*)d_in[3];
  const float* beta = (const float*)d_in[4];
  float* out = (float*)d_out;

  unsigned short* xb = (unsigned short*)d_ws;   // 4718592 us (tiled)
  unsigned short* Wsb = xb + 4718592;           // 393216 us  (tiled)
  unsigned short* Wcb = Wsb + 393216;           // 110592 us
  unsigned short* gsmb = Wcb + 110592;          // 829440 us   [45col][2img][9216]
  unsigned short* z = gsmb + 829440;            // 28311552 us [6][256][2][9216] packed
  float* yacc = (float*)(z + 28311552);         // 4718592 f32 [img][ch][p]
  float* stats = yacc + 4718592;                // 512 f32
  // zero guard (128 shorts) directly after stats; index relative to z:
  const unsigned guard_idx = 28311552u + 9437184u + 1024u;  // shorts

  hipMemsetAsync(stats, 0, 512 * sizeof(float) + 256, stream);
  init_all<<<3120, 256, 0, stream>>>(x, Ws, Wc, xb, Wsb, Wcb);
  gemms<<<2016, 256, 0, stream>>>(xb, Wsb, Wcb, z, gsmb);
  accum_chw<<<2304, 256, 0, stream>>>(z, gsmb, yacc, stats, guard_idx);
  bn_apply<<<4608, 256, 0, stream>>>(yacc, stats, gamma, beta, out);
}

// Round 9
// 173.499 us; speedup vs baseline: 4.0169x; 1.0713x over previous
//
#include <hip/hip_runtime.h>

typedef __bf16 bf16x8 __attribute__((ext_vector_type(8)));
typedef float f32x4 __attribute__((ext_vector_type(4)));

#define HW 9216
#define ZSLAB 9216   // packed 96*96 elems per (sl,ch,img) slab — no pads
#define XTILE 32768  // shorts per xb/Wsb tile: 32 chunks x 128 rows x 8 elems
#define GUARDL 55296 // LDS guard slot (shorts): after the 6 staged slabs

__device__ __forceinline__ unsigned short f2bf(float f) {
  unsigned u = __float_as_uint(f);
  unsigned r = (u + 0x7FFFu + ((u >> 16) & 1u)) >> 16;
  return (unsigned short)r;
}
__device__ __forceinline__ float bf2f(unsigned short h) {
  return __uint_as_float(((unsigned)h) << 16);
}

__device__ __forceinline__ void async16(const unsigned short* g, unsigned short* l) {
  __builtin_amdgcn_global_load_lds(
      (const __attribute__((address_space(1))) unsigned int*)g,
      (__attribute__((address_space(3))) unsigned int*)l, 16, 0, 0);
}

// y[j] += w[j] * z[O+j], z drawn from the 16-elem window {lo,hi}, O compile-time
template <int O>
__device__ __forceinline__ void tapfma(float* y, uint4 lo, uint4 hi, uint4 wv) {
  const unsigned short* lu = (const unsigned short*)&lo;
  const unsigned short* hu = (const unsigned short*)&hi;
  const unsigned short* wu = (const unsigned short*)&wv;
#pragma unroll
  for (int j = 0; j < 8; ++j) {
    unsigned short zz = (O + j < 8) ? lu[O + j] : hu[O + j - 8];
    y[j] += bf2f(wu[j]) * bf2f(zz);
  }
}

// guarded 16B LDS window read: invalid -> zeroed guard slot
__device__ __forceinline__ uint4 lload(const unsigned short* lz, bool v, int idx) {
  return *(const uint4*)(lz + (v ? idx : GUARDL));
}

// one 9-tap branch, windows read from LDS slab (slab B staged at B*9216).
template <int B, int D>
__device__ __forceinline__ void branchL(float* y, const unsigned short* lz,
                                        const unsigned short* __restrict__ gb,
                                        int h, int w0) {
  const int sbase = B * 9216;
  const bool cmv = ((unsigned)(w0 - ((D == 1 || D == 6) ? 8 : (D == 12 ? 16 : (D == 24 ? 24 : 40)))) <= 88u);
  const bool cm2v = ((unsigned)(w0 - ((D == 12) ? 8 : 32)) <= 88u);   // D12/D36 only
  const bool cpv = ((unsigned)(w0 + ((D == 1 || D == 6) ? 8 : (D == 12 ? 16 : (D == 24 ? 24 : 40)))) <= 88u);
  const bool cp2v = ((unsigned)(w0 + ((D == 12) ? 8 : 32)) <= 88u);   // D12/D36 only

#pragma unroll
  for (int r = 0; r < 3; ++r) {
    int hh = h + (r - 1) * D;
    bool rv = ((unsigned)hh < 96u);
    int rb = sbase + hh * 96;
    const int K0 = (B - 1) * 9 + r * 3;
    uint4 wv0 = *(const uint4*)(gb + (size_t)((K0 + 0) * 2) * HW);
    uint4 wv1 = *(const uint4*)(gb + (size_t)((K0 + 1) * 2) * HW);
    uint4 wv2 = *(const uint4*)(gb + (size_t)((K0 + 2) * 2) * HW);
    if constexpr (D == 1 || D == 6) {
      uint4 Wm = lload(lz, rv && cmv, rb + w0 - 8);
      uint4 W0 = lload(lz, rv, rb + w0);
      uint4 Wp = lload(lz, rv && cpv, rb + w0 + 8);
      if constexpr (D == 1) {
        tapfma<7>(y, Wm, W0, wv0);
        tapfma<0>(y, W0, W0, wv1);
        tapfma<1>(y, W0, Wp, wv2);
      } else {
        tapfma<2>(y, Wm, W0, wv0);
        tapfma<0>(y, W0, W0, wv1);
        tapfma<6>(y, W0, Wp, wv2);
      }
    } else if constexpr (D == 24) {
      uint4 Wm = lload(lz, rv && cmv, rb + w0 - 24);
      uint4 W0 = lload(lz, rv, rb + w0);
      uint4 Wp = lload(lz, rv && cpv, rb + w0 + 24);
      tapfma<0>(y, Wm, Wm, wv0);
      tapfma<0>(y, W0, W0, wv1);
      tapfma<0>(y, Wp, Wp, wv2);
    } else {  // D == 12 or 36; outer taps use O=4 with two windows each
      constexpr int co = (D == 12) ? 16 : 40;
      constexpr int ci = (D == 12) ? 8 : 32;
      uint4 Wa = lload(lz, rv && cmv, rb + w0 - co);
      uint4 Wb = lload(lz, rv && cm2v, rb + w0 - ci);
      uint4 W0 = lload(lz, rv, rb + w0);
      uint4 Wc = lload(lz, rv && cp2v, rb + w0 + ci);
      uint4 Wd = lload(lz, rv && cpv, rb + w0 + co);
      tapfma<4>(y, Wa, Wb, wv0);
      tapfma<0>(y, W0, W0, wv1);
      tapfma<4>(y, Wc, Wd, wv2);
    }
  }
}

// ---------- init: xpose into tiled layout | weight repack (tiled Wsb) ----------
// xb tiled: [144 tiles(128 rows)][32 chunks(8 k)][128 rows][8] shorts
__global__ __launch_bounds__(256) void init_all(const float* __restrict__ x,
                                                const float* __restrict__ Ws,
                                                const float* __restrict__ Wc,
                                                unsigned short* __restrict__ xb,
                                                unsigned short* __restrict__ Wsb,
                                                unsigned short* __restrict__ Wcb) {
  __shared__ float tile[64][65];
  int id = blockIdx.x;
  int t = threadIdx.x;
  if (id < 1152) {  // xpose
    int bx = id % 144, by = (id / 144) % 4, n = id / 576;
    int p0 = bx * 64, ci0 = by * 64;
    int cl = t & 63, q = t >> 6;
#pragma unroll
    for (int i = 0; i < 16; ++i) {
      int cir = q + i * 4;
      tile[cir][cl] = x[((size_t)(n * 256 + ci0 + cir)) * HW + p0 + cl];
    }
    __syncthreads();
    // write: lane = row, 2 uint4 (=2 chunks of 8 ch) per thread, contiguous
    int R = n * HW + p0 + cl;
    int Rt = R >> 7, Rl = R & 127;
#pragma unroll
    for (int i = 0; i < 2; ++i) {
      int cloc = q * 2 + i;  // chunk-local 0..7
      unsigned rr[4];
#pragma unroll
      for (int jj = 0; jj < 4; ++jj) {
        unsigned short a = f2bf(tile[cloc * 8 + jj * 2][cl]);
        unsigned short b = f2bf(tile[cloc * 8 + jj * 2 + 1][cl]);
        rr[jj] = (unsigned)a | ((unsigned)b << 16);
      }
      *(uint4*)(xb + (size_t)Rt * XTILE + (by * 8 + cloc) * 1024 + Rl * 8) =
          make_uint4(rr[0], rr[1], rr[2], rr[3]);
    }
  } else {  // weight repack
    int u = (id - 1152) * 256 + t;
    if (u < 393216) {  // Wsb tiled: [12 tiles][32 chunks][128 rows][8]
      int r = u >> 8, k = u & 255;
      Wsb[(size_t)(r >> 7) * XTILE + (k >> 3) * 1024 + (r & 127) * 8 + (k & 7)] =
          f2bf(Ws[(size_t)(r & 255) * 1536 + (r >> 8) * 256 + k]);
    } else {
      int v = u - 393216;
      if (v < 110592) {
        int co = v / 2304, rr = v % 2304;
        int j = rr >> 8, ci = rr & 255;
        Wcb[v] = (co < 45) ? f2bf(Wc[(size_t)co * 2304 + ci * 9 + j]) : (unsigned short)0;
      }
    }
  }
}

// ---------- gemms: gemm_g first (288 blocks) | gemm_z (contiguous DMA) ----------
__global__ __launch_bounds__(256) void gemms(const unsigned short* __restrict__ xb,
                                             const unsigned short* __restrict__ Wsb,
                                             const unsigned short* __restrict__ Wcb,
                                             unsigned short* __restrict__ z,
                                             unsigned short* __restrict__ gsmb) {
  __shared__ unsigned short smem[16384];  // 32KB
  int id = blockIdx.x;
  int t = threadIdx.x;
  int wid = t >> 6, lane = t & 63;
  int q = lane >> 4, ln = lane & 15;

  if (id < 288) {
    // ===== gemm_g: BM=64 BN=48 BK=64 (36 steps), reg-prefetch, fused softmax =====
    unsigned short* As = smem;          // 8 kq x 64 mm x uint4 = 8KB
    unsigned short* Bs = smem + 4096;   // 8 kq x 48 nn x uint4 = 6KB
    int m0 = id * 64;
    int mm = t >> 2, kq = t & 3;
    int m = m0 + mm;
    int img = m / HW, p = m % HW;
    int h = p / 96, w = p % 96;
    int mbase = img * HW;
    int nn = t >> 2;  // for Bs (t<192)
    f32x4 acc[3] = {};
    uint4 aA0, aA1, aB0, aB1;

    // prefetch step 0 (tap j=0 -> dy=-1,dx=-1; chunks kq, kq+4 of tile)
    {
      int hh = h - 1, ww = w - 1;
      bool valid = ((unsigned)hh < 96u) & ((unsigned)ww < 96u);
      int R = mbase + hh * 96 + ww;
      const unsigned short* pa =
          xb + (long)(R >> 7) * XTILE + kq * 1024 + (R & 127) * 8;
      aA0 = valid ? *(const uint4*)pa : make_uint4(0, 0, 0, 0);
      aA1 = valid ? *(const uint4*)(pa + 4096) : make_uint4(0, 0, 0, 0);
      if (t < 192) {
        const unsigned short* pb = Wcb + (size_t)nn * 2304 + kq * 8;
        aB0 = *(const uint4*)pb;
        aB1 = *(const uint4*)(pb + 32);
      }
    }

    for (int s = 0; s < 36; ++s) {
      ((uint4*)As)[kq * 64 + mm] = aA0;
      ((uint4*)As)[(kq + 4) * 64 + mm] = aA1;
      if (t < 192) {
        ((uint4*)Bs)[kq * 48 + nn] = aB0;
        ((uint4*)Bs)[(kq + 4) * 48 + nn] = aB1;
      }
      __syncthreads();
      if (s + 1 < 36) {  // prefetch next step; consumed next iteration
        int s1 = s + 1;
        int j = s1 >> 2;
        int hh = h + j / 3 - 1, ww = w + j % 3 - 1;
        bool valid = ((unsigned)hh < 96u) & ((unsigned)ww < 96u);
        int R = mbase + hh * 96 + ww;
        const unsigned short* pa = xb + (long)(R >> 7) * XTILE +
                                   ((s1 & 3) * 8 + kq) * 1024 + (R & 127) * 8;
        aA0 = valid ? *(const uint4*)pa : make_uint4(0, 0, 0, 0);
        aA1 = valid ? *(const uint4*)(pa + 4096) : make_uint4(0, 0, 0, 0);
        if (t < 192) {
          const unsigned short* pb = Wcb + (size_t)nn * 2304 + s1 * 64 + kq * 8;
          aB0 = *(const uint4*)pb;
          aB1 = *(const uint4*)(pb + 32);
        }
      }
#pragma unroll
      for (int kk = 0; kk < 2; ++kk) {
        bf16x8 a = ((const bf16x8*)As)[(kk * 4 + q) * 64 + wid * 16 + ln];
#pragma unroll
        for (int fn = 0; fn < 3; ++fn) {
          bf16x8 b = ((const bf16x8*)Bs)[(kk * 4 + q) * 48 + fn * 16 + ln];
          acc[fn] = __builtin_amdgcn_mfma_f32_16x16x32_bf16(a, b, acc[fn], 0, 0, 0);
        }
      }
      __syncthreads();
    }

    // fused softmax epilogue: acc -> LDS f32 [64px][49], then 64 threads softmax
    float* LDSf = (float*)smem;  // 64*49*4 = 12544B
#pragma unroll
    for (int fn = 0; fn < 3; ++fn)
#pragma unroll
      for (int r = 0; r < 4; ++r)
        LDSf[(wid * 16 + q * 4 + r) * 49 + fn * 16 + ln] = acc[fn][r];
    __syncthreads();
    if (t < 64) {
      const float* row = LDSf + t * 49;
      int mg = m0 + t;
      int img2 = mg / HW, p2 = mg - img2 * HW;
      for (int grp = 0; grp < 5; ++grp) {
        float v[9], mx = -1e30f;
#pragma unroll
        for (int k = 0; k < 9; ++k) { v[k] = row[grp * 9 + k]; mx = fmaxf(mx, v[k]); }
        float sum = 0.f;
#pragma unroll
        for (int k = 0; k < 9; ++k) { v[k] = __expf(v[k] - mx); sum += v[k]; }
        float inv = 1.f / sum;
#pragma unroll
        for (int k = 0; k < 9; ++k) {
          int col = grp * 9 + k;
          gsmb[((size_t)(col * 2 + img2)) * HW + p2] = f2bf(v[k] * inv);
        }
      }
    }
  } else {
    // ===== gemm_z: 128x128, K=256, double-buffered FULLY-CONTIGUOUS DMA =====
    int zid = id - 288;
    int mt = zid % 144, ct = zid / 144;
    int m0 = mt * 128, c0 = ct * 128;
    int wm = (wid >> 1) * 64, wn = (wid & 1) * 64;
    bool isB = wid >= 2;
    // tiled source: per K-step the 8KB stage region is linear
    const unsigned short* gsrc =
        (isB ? Wsb + (size_t)ct * XTILE : xb + (size_t)mt * XTILE) + lane * 8;
    unsigned short* lb = smem + (isB ? 8192 : 0);
    int ow = (wid & 1) * 4;  // op offset: waves {0,2}->0..3, {1,3}->4..7
    f32x4 acc[4][4] = {};

    // stage step 0 into buffer 0
#pragma unroll
    for (int kq = 0; kq < 4; ++kq)
      async16(gsrc + (ow + kq) * 512, lb + (ow + kq) * 512);
    __syncthreads();

    for (int s = 0; s < 8; ++s) {
      int cur = s & 1, nxt = cur ^ 1;
      if (s < 7) {  // issue next-step DMA; drained by end-of-iter barrier
#pragma unroll
        for (int kq = 0; kq < 4; ++kq)
          async16(gsrc + (s + 1) * 4096 + (ow + kq) * 512,
                  lb + nxt * 4096 + (ow + kq) * 512);
      }
      const unsigned short* Asc = smem + cur * 4096;
      const unsigned short* Bsc = smem + 8192 + cur * 4096;
      bf16x8 a[4], b[4];
#pragma unroll
      for (int f = 0; f < 4; ++f) {
        a[f] = ((const bf16x8*)Asc)[q * 128 + wm + f * 16 + ln];
        b[f] = ((const bf16x8*)Bsc)[q * 128 + wn + f * 16 + ln];
      }
#pragma unroll
      for (int fm = 0; fm < 4; ++fm)
#pragma unroll
        for (int fn = 0; fn < 4; ++fn)
          acc[fm][fn] = __builtin_amdgcn_mfma_f32_16x16x32_bf16(a[fm], b[fn], acc[fm][fn], 0, 0, 0);
      __syncthreads();
    }

    // epilogue: packed z; per-channel 256B contiguous line-aligned runs
    int sl = c0 >> 8, cb = c0 & 255;
    int img = m0 / HW;
    int pbase = m0 - img * HW;
#pragma unroll
    for (int fm = 0; fm < 4; ++fm) {
      int p = pbase + wm + fm * 16 + q * 4;
#pragma unroll
      for (int fn = 0; fn < 4; ++fn) {
        int ch = cb + wn + fn * 16 + ln;
        size_t slab = ((size_t)(sl * 256 + ch) * 2 + img) * ZSLAB;
        unsigned lo = (unsigned)f2bf(acc[fm][fn][0]) | ((unsigned)f2bf(acc[fm][fn][1]) << 16);
        unsigned hi = (unsigned)f2bf(acc[fm][fn][2]) | ((unsigned)f2bf(acc[fm][fn][3]) << 16);
        *(uint2*)(z + slab + p) = make_uint2(lo, hi);
      }
    }
  }
}

// ---------- accum: one block per (ch,img); all 6 z-slabs staged in LDS --------
// 512 blocks x 576 thr (9 waves), 110.6KB LDS -> 1 block/CU, 2 clean cohorts.
// Staging: 108 contiguous 1KB async16 wave-ops (12 per wave). All window
// reads are ds_read_b128; guard slot in LDS handles out-of-image taps.
__global__ __launch_bounds__(576, 1) void accum_chw(const unsigned short* __restrict__ z,
                                                    const unsigned short* __restrict__ gsmb,
                                                    float* __restrict__ yacc,
                                                    float* __restrict__ stats) {
  extern __shared__ unsigned short lz[];  // 6*9216 + 16 shorts = 110624 B
  int bid = blockIdx.x;
  int img = bid & 1, ch = bid >> 1;
  int t = threadIdx.x;
  int wv_id = t >> 6, lane = t & 63;

  // stage 6 slabs (each 18432B = 18 ops); op -> slab s = op/18, off = (op%18)*512
#pragma unroll
  for (int i = 0; i < 12; ++i) {
    int op = wv_id + i * 9;
    int s = op / 18;
    int off = (op - s * 18) * 512;  // shorts
    async16(z + ((size_t)((s * 256 + ch) * 2 + img)) * ZSLAB + off + lane * 8,
            lz + s * 9216 + off);
  }
  if (t == 0) *(uint4*)(lz + GUARDL) = make_uint4(0u, 0u, 0u, 0u);
  __syncthreads();  // drains vmcnt+lgkmcnt

  float s1 = 0.f, s2 = 0.f;
#pragma unroll
  for (int rep = 0; rep < 2; ++rep) {
    int c = t + rep * 576;          // chunk 0..1151
    int h = c / 12;
    int w0 = (c - h * 12) * 8;
    int p0 = h * 96 + w0;
    const unsigned short* gb = gsmb + (size_t)img * HW + p0;

    float y[8];
    {  // identity from LDS slab 0
      uint4 v = *(const uint4*)(lz + p0);
      const unsigned short* u = (const unsigned short*)&v;
#pragma unroll
      for (int j = 0; j < 8; ++j) y[j] = bf2f(u[j]);
    }
    branchL<1, 1>(y, lz, gb, h, w0);
    branchL<2, 6>(y, lz, gb, h, w0);
    branchL<3, 12>(y, lz, gb, h, w0);
    branchL<4, 24>(y, lz, gb, h, w0);
    branchL<5, 36>(y, lz, gb, h, w0);

    size_t ybase = ((size_t)(img * 256 + ch)) * HW + p0;
    *(float4*)(yacc + ybase) = make_float4(y[0], y[1], y[2], y[3]);
    *(float4*)(yacc + ybase + 4) = make_float4(y[4], y[5], y[6], y[7]);

#pragma unroll
    for (int j = 0; j < 8; ++j) { s1 += y[j]; s2 += y[j] * y[j]; }
  }

#pragma unroll
  for (int off = 1; off <= 32; off <<= 1) {
    s1 += __shfl_xor(s1, off);
    s2 += __shfl_xor(s2, off);
  }
  if (lane == 0) {  // whole block is one ch: 9 waves x 2 atomics
    atomicAdd(&stats[ch], s1);
    atomicAdd(&stats[256 + ch], s2);
  }
}

// ---------- bn: elementwise on CHW ----------
__global__ __launch_bounds__(256) void bn_apply(const float* __restrict__ yacc,
                                                const float* __restrict__ stats,
                                                const float* __restrict__ gamma,
                                                const float* __restrict__ beta,
                                                float* __restrict__ out) {
  int q = blockIdx.x * 256 + threadIdx.x;
  int ch = (q / 2304) & 255;
  const float inv_cnt = 1.f / 18432.f;
  float mean = stats[ch] * inv_cnt;
  float var = stats[256 + ch] * inv_cnt - mean * mean;
  float sc = rsqrtf(var + 1e-5f) * gamma[ch];
  float sh = beta[ch] - mean * sc;
  float4 v = *(const float4*)(yacc + (size_t)q * 4);
  float4 o = make_float4(v.x * sc + sh, v.y * sc + sh, v.z * sc + sh, v.w * sc + sh);
  *(float4*)(out + (size_t)q * 4) = o;
}

extern "C" void kernel_launch(void* const* d_in, const int* in_sizes, int n_in,
                              void* d_out, int out_size, void* d_ws, size_t ws_size,
                              hipStream_t stream) {
  const float* x = (const float*)d_in[0];
  const float* Wc = (const float*)d_in[1];
  const float* Ws = (const float*)d_in[2];
  const float* gamma = (const float*)d_in[3];
  const float* beta = (const float*)d_in[4];
  float* out = (float*)d_out;

  unsigned short* xb = (unsigned short*)d_ws;   // 4718592 us (tiled)
  unsigned short* Wsb = xb + 4718592;           // 393216 us  (tiled)
  unsigned short* Wcb = Wsb + 393216;           // 110592 us
  unsigned short* gsmb = Wcb + 110592;          // 829440 us   [45col][2img][9216]
  unsigned short* z = gsmb + 829440;            // 28311552 us [6][256][2][9216] packed
  float* yacc = (float*)(z + 28311552);         // 4718592 f32 [img][ch][p]
  float* stats = yacc + 4718592;                // 512 f32

  hipMemsetAsync(stats, 0, 512 * sizeof(float), stream);
  init_all<<<3120, 256, 0, stream>>>(x, Ws, Wc, xb, Wsb, Wcb);
  gemms<<<2016, 256, 0, stream>>>(xb, Wsb, Wcb, z, gsmb);
  accum_chw<<<512, 576, 110624, stream>>>(z, gsmb, yacc, stats);
  bn_apply<<<4608, 256, 0, stream>>>(yacc, stats, gamma, beta, out);
}